// Round 1
// baseline (761.267 us; speedup 1.0000x reference)
//
#include <hip/hip_runtime.h>
#include <math.h>

#define TT 84
#define BB 96
#define HH 10
#define NTOK (TT*BB)   // 8064

// xp  layout: [dir][t][g][b]   (g in 0..29; b fastest for coalescing)
// act layout: [c][t][b], c = dir*10 + j   (20 channels)

__global__ __launch_bounds__(256) void proj0_kernel(
    const int* __restrict__ x, const float* __restrict__ emb,
    const float* __restrict__ wih0, const float* __restrict__ bih0,
    float* __restrict__ xp)
{
    __shared__ float4 xrow[32][100];   // 32 tokens x 400 floats
    const int tok0 = blockIdx.x * 32;
    for (int u = threadIdx.x; u < 32*100; u += 256) {
        int tk = u / 100, i4 = u % 100;
        int row = x[tok0 + tk];
        xrow[tk][i4] = ((const float4*)emb)[row*100 + i4];
    }
    __syncthreads();
    const int g64 = threadIdx.x & 63;
    const int q   = threadIdx.x >> 6;          // 0..3, 8 tokens each
    if (g64 >= 60) return;
    const int dir = g64 / 30, gg = g64 % 30;
    const float bias = bih0[dir*30 + gg];
    float acc[8];
    #pragma unroll
    for (int c = 0; c < 8; ++c) acc[c] = bias;
    const float4* w4 = ((const float4*)wih0) + (dir*30 + gg)*100;
    for (int i4 = 0; i4 < 100; ++i4) {
        float4 w = w4[i4];
        #pragma unroll
        for (int c = 0; c < 8; ++c) {
            float4 xv = xrow[q*8 + c][i4];
            acc[c] += w.x*xv.x + w.y*xv.y + w.z*xv.z + w.w*xv.w;
        }
    }
    #pragma unroll
    for (int c = 0; c < 8; ++c) {
        int tok = tok0 + q*8 + c;
        int t = tok / BB, b = tok % BB;
        xp[((dir*TT + t)*30 + gg)*BB + b] = acc[c];
    }
}

// layers 1..9: xp = act(20ch) @ w_ih^T + b_ih ; one thread per output element
__global__ __launch_bounds__(256) void proj_kernel(
    const float* __restrict__ act, const float* __restrict__ wih,
    const float* __restrict__ bih, float* __restrict__ xp)
{
    int idx = blockIdx.x*256 + threadIdx.x;
    if (idx >= 2*30*NTOK) return;
    int b   = idx % BB;
    int t   = (idx / BB) % TT;
    int g   = (idx / NTOK) % 30;
    int dir = idx / (30*NTOK);
    const float* w = wih + (dir*30 + g)*20;
    float acc = bih[dir*30 + g];
    #pragma unroll
    for (int i = 0; i < 20; ++i)
        acc += act[i*NTOK + t*BB + b] * w[i];
    xp[((dir*TT + t)*30 + g)*BB + b] = acc;
}

// sequential GRU scan; grid = 12 blocks (2 dir x 6 batch-groups), block = 160
__global__ __launch_bounds__(160) void scan_kernel(
    const float* __restrict__ xp, const float* __restrict__ whh,
    const float* __restrict__ bhh, float* __restrict__ act)
{
    const int j   = threadIdx.x / 16;          // 0..9  hidden idx
    const int bl  = threadIdx.x % 16;          // 0..15 batch within block
    const int dir = blockIdx.x & 1;
    const int b   = (blockIdx.x >> 1)*16 + bl;

    float wr[HH], wz[HH], wn[HH];
    const float* wb = whh + dir*3*HH*HH;
    #pragma unroll
    for (int k = 0; k < HH; ++k) {
        wr[k] = wb[(j     )*HH + k];
        wz[k] = wb[(HH+j  )*HH + k];
        wn[k] = wb[(2*HH+j)*HH + k];
    }
    const float br = bhh[dir*30 + j];
    const float bz = bhh[dir*30 + HH + j];
    const float bn = bhh[dir*30 + 2*HH + j];

    __shared__ float h[2][HH][16];
    h[0][j][bl] = 0.f;
    __syncthreads();

    const float* xb = xp + dir*(TT*30*BB) + b;
    float* ab = act + (dir*HH + j)*NTOK + b;
    int p = 0;
    for (int s = 0; s < TT; ++s) {
        int t = dir ? (TT-1-s) : s;
        const float* xt = xb + t*30*BB;
        float xr = xt[j*BB], xz = xt[(HH+j)*BB], xn = xt[(2*HH+j)*BB];
        float hr = br, hz = bz, hn = bn;
        #pragma unroll
        for (int k = 0; k < HH; ++k) {
            float hk = h[p][k][bl];
            hr += wr[k]*hk; hz += wz[k]*hk; hn += wn[k]*hk;
        }
        float hprev = h[p][j][bl];
        float r = 1.f/(1.f + __expf(-(xr+hr)));
        float z = 1.f/(1.f + __expf(-(xz+hz)));
        float n = tanhf(xn + r*hn);
        float hnew = (1.f - z)*n + z*hprev;
        h[1-p][j][bl] = hnew;
        ab[t*BB] = hnew;
        p ^= 1;
        __syncthreads();
    }
}

// head: pooling over (i,kk) of act[:18], then 96 rows x (336 -> 19) + sigmoid
__global__ __launch_bounds__(64) void head_kernel(
    const float* __restrict__ act, const float* __restrict__ lin_w,
    const float* __restrict__ lin_b, float* __restrict__ out)
{
    __shared__ float feat[336];
    const int r = blockIdx.x;   // 0..95
    for (int u = threadIdx.x; u < 336; u += 64) {
        int q = u / 12, f = u % 12;
        int pair = r*28 + q;            // t*32 + bb
        int t = pair / 32, bb = pair % 32;
        int jj = (f < 6) ? f : f - 6;
        float acc = (f < 6) ? 0.f : -1e30f;
        #pragma unroll
        for (int i = 0; i < 3; ++i) {
            #pragma unroll
            for (int kk = 0; kk < 3; ++kk) {
                int c = jj*3 + kk, b = bb*3 + i;
                float v = act[c*NTOK + t*BB + b];
                if (f < 6) acc += v; else acc = fmaxf(acc, v);
            }
        }
        feat[u] = (f < 6) ? acc*(1.f/9.f) : acc;
    }
    __syncthreads();
    for (int o = threadIdx.x; o < 19; o += 64) {
        float acc = lin_b[o];
        for (int q = 0; q < 336; ++q) acc += feat[q]*lin_w[o*336 + q];
        out[r*19 + o] = 1.f/(1.f + __expf(-acc));
    }
}

extern "C" void kernel_launch(void* const* d_in, const int* in_sizes, int n_in,
                              void* d_out, int out_size, void* d_ws, size_t ws_size,
                              hipStream_t stream)
{
    const int*   x     = (const int*)  d_in[0];
    const float* emb   = (const float*)d_in[1];
    const float* wih0  = (const float*)d_in[2];
    const float* whh0  = (const float*)d_in[3];
    const float* bih0  = (const float*)d_in[4];
    const float* bhh0  = (const float*)d_in[5];
    const float* wih   = (const float*)d_in[6];
    const float* whh   = (const float*)d_in[7];
    const float* bih   = (const float*)d_in[8];
    const float* bhh   = (const float*)d_in[9];
    const float* lin_w = (const float*)d_in[10];
    const float* lin_b = (const float*)d_in[11];
    float* out = (float*)d_out;

    float* xp  = (float*)d_ws;             // 2*84*30*96 = 483840 floats (1.94 MB)
    float* act = xp + 2*30*NTOK;           // 20*8064   = 161280 floats (0.65 MB)

    proj0_kernel<<<252, 256, 0, stream>>>(x, emb, wih0, bih0, xp);
    scan_kernel<<<12, 160, 0, stream>>>(xp, whh0, bhh0, act);
    for (int l = 1; l < 10; ++l) {
        proj_kernel<<<1890, 256, 0, stream>>>(act, wih + (l-1)*2*30*20,
                                              bih + (l-1)*2*30, xp);
        scan_kernel<<<12, 160, 0, stream>>>(xp, whh + (l-1)*2*30*10,
                                            bhh + (l-1)*2*30, act);
    }
    head_kernel<<<96, 64, 0, stream>>>(act, lin_w, lin_b, out);
}

// Round 2
// 652.410 us; speedup vs baseline: 1.1669x; 1.1669x over previous
//
#include <hip/hip_runtime.h>
#include <math.h>

#define TT 84
#define BB 96
#define HH 10
#define NTOK (TT*BB)   // 8064

// Layouts:
//   xp0 (layer-0 gate inputs): [dir][t][b][30]
//   act (layer outputs):       [t][b][20], c = dir*10 + j
// Scan kernels: 1 wave per (dir, 6-batch group) -> 32 blocks x 64 threads.
// No __syncthreads in the recurrent loop: h exchanged via ds_bpermute.

__device__ __forceinline__ float sigm(float x)  { return 1.f/(1.f + __expf(-x)); }
__device__ __forceinline__ float ftanh(float x) { return 1.f - 2.f/(1.f + __expf(2.f*x)); }

// ---------------- layer-0 projection: emb gather + E=400 dot ----------------
__global__ __launch_bounds__(256) void proj0_kernel(
    const int* __restrict__ x, const float* __restrict__ emb,
    const float* __restrict__ wih0, const float* __restrict__ bih0,
    float* __restrict__ xp)
{
    __shared__ float4 xrow[32][100];   // 32 tokens x 400 floats
    const int tok0 = blockIdx.x * 32;
    for (int u = threadIdx.x; u < 32*100; u += 256) {
        int tk = u / 100, i4 = u % 100;
        int row = x[tok0 + tk];
        xrow[tk][i4] = ((const float4*)emb)[row*100 + i4];
    }
    __syncthreads();
    const int g64 = threadIdx.x & 63;
    const int q   = threadIdx.x >> 6;          // 0..3, 8 tokens each
    if (g64 >= 60) return;
    const int dir = g64 / 30, gg = g64 % 30;
    const float bias = bih0[dir*30 + gg];
    float acc[8];
    #pragma unroll
    for (int c = 0; c < 8; ++c) acc[c] = bias;
    const float4* w4 = ((const float4*)wih0) + (dir*30 + gg)*100;
    for (int i4 = 0; i4 < 100; ++i4) {
        float4 w = w4[i4];
        #pragma unroll
        for (int c = 0; c < 8; ++c) {
            float4 xv = xrow[q*8 + c][i4];
            acc[c] += w.x*xv.x + w.y*xv.y + w.z*xv.z + w.w*xv.w;
        }
    }
    #pragma unroll
    for (int c = 0; c < 8; ++c) {
        int tok = tok0 + q*8 + c;
        int t = tok / BB, b = tok % BB;
        xp[((size_t)((dir*TT + t)*BB + b))*30 + gg] = acc[c];
    }
}

// ---------------- layer-0 scan: reads precomputed xp ----------------
__global__ __launch_bounds__(64) void scan0_kernel(
    const float* __restrict__ xp, const float* __restrict__ whhL,
    const float* __restrict__ bhhL, float* __restrict__ act)
{
    const int lane = threadIdx.x;
    int bl = lane / 10; if (bl > 5) bl = 5;
    int j  = lane - bl*10; if (j > 9) j = 9;
    const bool activeL = (lane < 60);
    const int dir = blockIdx.x & 1;
    const int b   = (blockIdx.x >> 1)*6 + bl;

    float wr[10], wz[10], wn[10];
    const float* wh = whhL + dir*300;
    #pragma unroll
    for (int k = 0; k < 10; ++k) {
        wr[k] = wh[(j     )*10 + k];
        wz[k] = wh[(10 + j)*10 + k];
        wn[k] = wh[(20 + j)*10 + k];
    }
    const float bhr = bhhL[dir*30 + j];
    const float bhz = bhhL[dir*30 + 10 + j];
    const float bhn = bhhL[dir*30 + 20 + j];

    float h[10];
    #pragma unroll
    for (int k = 0; k < 10; ++k) h[k] = 0.f;
    float hown = 0.f;
    const int gb = bl*10*4;

    const int dt = dir ? -1 : 1;
    int t = dir ? TT-1 : 0;
    const float* xb = xp + (size_t)dir*TT*BB*30;

    float xr = xb[(size_t)(t*BB + b)*30 + j];
    float xz = xb[(size_t)(t*BB + b)*30 + 10 + j];
    float xn = xb[(size_t)(t*BB + b)*30 + 20 + j];

    for (int s = 0; s < TT; ++s) {
        int tn = (s == TT-1) ? t : t + dt;
        float nxr = xb[(size_t)(tn*BB + b)*30 + j];
        float nxz = xb[(size_t)(tn*BB + b)*30 + 10 + j];
        float nxn = xb[(size_t)(tn*BB + b)*30 + 20 + j];

        float hr0 = bhr, hz0 = bhz, hn0 = bhn, hr1 = 0.f, hz1 = 0.f, hn1 = 0.f;
        #pragma unroll
        for (int k = 0; k < 10; k += 2) {
            hr0 = fmaf(wr[k], h[k], hr0); hr1 = fmaf(wr[k+1], h[k+1], hr1);
            hz0 = fmaf(wz[k], h[k], hz0); hz1 = fmaf(wz[k+1], h[k+1], hz1);
            hn0 = fmaf(wn[k], h[k], hn0); hn1 = fmaf(wn[k+1], h[k+1], hn1);
        }
        float r = sigm(xr + hr0 + hr1);
        float z = sigm(xz + hz0 + hz1);
        float n = ftanh(xn + r*(hn0 + hn1));
        float hnew = n + z*(hown - n);
        if (activeL) act[(size_t)(t*BB + b)*20 + dir*10 + j] = hnew;
        hown = hnew;
        int hv = __float_as_int(hnew);
        #pragma unroll
        for (int k = 0; k < 10; ++k)
            h[k] = __int_as_float(__builtin_amdgcn_ds_bpermute(gb + k*4, hv));
        xr = nxr; xz = nxz; xn = nxn;
        t = tn;
    }
}

// -------- layers 1..9: fused (xp projection + scan), no separate proj --------
__global__ __launch_bounds__(64) void fscan_kernel(
    const float* __restrict__ actp, const float* __restrict__ wihL,
    const float* __restrict__ bihL, const float* __restrict__ whhL,
    const float* __restrict__ bhhL, float* __restrict__ act)
{
    const int lane = threadIdx.x;
    int bl = lane / 10; if (bl > 5) bl = 5;
    int j  = lane - bl*10; if (j > 9) j = 9;
    const bool activeL = (lane < 60);
    const int dir = blockIdx.x & 1;
    const int b   = (blockIdx.x >> 1)*6 + bl;

    // input-projection weights (3 rows of 20)
    float wpr[20], wpz[20], wpn[20];
    const float* wi = wihL + dir*600;
    #pragma unroll
    for (int c = 0; c < 20; ++c) {
        wpr[c] = wi[(j     )*20 + c];
        wpz[c] = wi[(10 + j)*20 + c];
        wpn[c] = wi[(20 + j)*20 + c];
    }
    const float bir = bihL[dir*30 + j];
    const float biz = bihL[dir*30 + 10 + j];
    const float bin = bihL[dir*30 + 20 + j];

    // recurrent weights (3 rows of 10)
    float wr[10], wz[10], wn[10];
    const float* wh = whhL + dir*300;
    #pragma unroll
    for (int k = 0; k < 10; ++k) {
        wr[k] = wh[(j     )*10 + k];
        wz[k] = wh[(10 + j)*10 + k];
        wn[k] = wh[(20 + j)*10 + k];
    }
    const float bhr = bhhL[dir*30 + j];
    const float bhz = bhhL[dir*30 + 10 + j];
    const float bhn = bhhL[dir*30 + 20 + j];

    float h[10];
    #pragma unroll
    for (int k = 0; k < 10; ++k) h[k] = 0.f;
    float hown = 0.f;
    const int gb = bl*10*4;

    const int dt = dir ? -1 : 1;
    int t = dir ? TT-1 : 0;

    float4 A[5];
    {
        const float4* p = (const float4*)(actp + (size_t)(t*BB + b)*20);
        #pragma unroll
        for (int q = 0; q < 5; ++q) A[q] = p[q];
    }

    for (int s = 0; s < TT; ++s) {
        // gate inputs for current t from prefetched A
        float xr = bir, xz = biz, xn = bin;
        #pragma unroll
        for (int q = 0; q < 5; ++q) {
            float av0 = A[q].x, av1 = A[q].y, av2 = A[q].z, av3 = A[q].w;
            int c = q*4;
            xr = fmaf(wpr[c  ], av0, xr); xz = fmaf(wpz[c  ], av0, xz); xn = fmaf(wpn[c  ], av0, xn);
            xr = fmaf(wpr[c+1], av1, xr); xz = fmaf(wpz[c+1], av1, xz); xn = fmaf(wpn[c+1], av1, xn);
            xr = fmaf(wpr[c+2], av2, xr); xz = fmaf(wpz[c+2], av2, xz); xn = fmaf(wpn[c+2], av2, xn);
            xr = fmaf(wpr[c+3], av3, xr); xz = fmaf(wpz[c+3], av3, xz); xn = fmaf(wpn[c+3], av3, xn);
        }
        // prefetch next step's activations (no h dependence)
        int tn = (s == TT-1) ? t : t + dt;
        {
            const float4* p = (const float4*)(actp + (size_t)(tn*BB + b)*20);
            #pragma unroll
            for (int q = 0; q < 5; ++q) A[q] = p[q];
        }
        // recurrent dots (2-way split chains)
        float hr0 = bhr, hz0 = bhz, hn0 = bhn, hr1 = 0.f, hz1 = 0.f, hn1 = 0.f;
        #pragma unroll
        for (int k = 0; k < 10; k += 2) {
            hr0 = fmaf(wr[k], h[k], hr0); hr1 = fmaf(wr[k+1], h[k+1], hr1);
            hz0 = fmaf(wz[k], h[k], hz0); hz1 = fmaf(wz[k+1], h[k+1], hz1);
            hn0 = fmaf(wn[k], h[k], hn0); hn1 = fmaf(wn[k+1], h[k+1], hn1);
        }
        float r = sigm(xr + hr0 + hr1);
        float z = sigm(xz + hz0 + hz1);
        float n = ftanh(xn + r*(hn0 + hn1));
        float hnew = n + z*(hown - n);
        if (activeL) act[(size_t)(t*BB + b)*20 + dir*10 + j] = hnew;
        hown = hnew;
        int hv = __float_as_int(hnew);
        #pragma unroll
        for (int k = 0; k < 10; ++k)
            h[k] = __int_as_float(__builtin_amdgcn_ds_bpermute(gb + k*4, hv));
        t = tn;
    }
}

// ---------------- head: pooling + 336->19 linear + sigmoid ----------------
__global__ __launch_bounds__(64) void head_kernel(
    const float* __restrict__ act, const float* __restrict__ lin_w,
    const float* __restrict__ lin_b, float* __restrict__ out)
{
    __shared__ float feat[336];
    const int r = blockIdx.x;   // 0..95
    for (int u = threadIdx.x; u < 336; u += 64) {
        int q = u / 12, f = u % 12;
        int pair = r*28 + q;            // t*32 + bb
        int t = pair / 32, bb = pair % 32;
        int jj = (f < 6) ? f : f - 6;
        float acc = (f < 6) ? 0.f : -1e30f;
        #pragma unroll
        for (int i = 0; i < 3; ++i) {
            #pragma unroll
            for (int kk = 0; kk < 3; ++kk) {
                int c = jj*3 + kk, b = bb*3 + i;
                float v = act[(size_t)(t*BB + b)*20 + c];
                if (f < 6) acc += v; else acc = fmaxf(acc, v);
            }
        }
        feat[u] = (f < 6) ? acc*(1.f/9.f) : acc;
    }
    __syncthreads();
    for (int o = threadIdx.x; o < 19; o += 64) {
        float acc = lin_b[o];
        for (int q = 0; q < 336; ++q) acc += feat[q]*lin_w[o*336 + q];
        out[r*19 + o] = sigm(acc);
    }
}

extern "C" void kernel_launch(void* const* d_in, const int* in_sizes, int n_in,
                              void* d_out, int out_size, void* d_ws, size_t ws_size,
                              hipStream_t stream)
{
    const int*   x     = (const int*)  d_in[0];
    const float* emb   = (const float*)d_in[1];
    const float* wih0  = (const float*)d_in[2];
    const float* whh0  = (const float*)d_in[3];
    const float* bih0  = (const float*)d_in[4];
    const float* bhh0  = (const float*)d_in[5];
    const float* wih   = (const float*)d_in[6];
    const float* whh   = (const float*)d_in[7];
    const float* bih   = (const float*)d_in[8];
    const float* bhh   = (const float*)d_in[9];
    const float* lin_w = (const float*)d_in[10];
    const float* lin_b = (const float*)d_in[11];
    float* out = (float*)d_out;

    float* xp0  = (float*)d_ws;               // 2*84*96*30 = 483840 floats
    float* actA = xp0 + 2*NTOK*30;            // 84*96*20 = 161280 floats
    float* actB = actA + NTOK*20;             // 161280 floats

    proj0_kernel<<<252, 256, 0, stream>>>(x, emb, wih0, bih0, xp0);
    scan0_kernel<<<32, 64, 0, stream>>>(xp0, whh0, bhh0, actA);

    float* src = actA;
    float* dst = actB;
    for (int l = 1; l < 10; ++l) {
        fscan_kernel<<<32, 64, 0, stream>>>(src,
                                            wih + (size_t)(l-1)*2*30*20,
                                            bih + (size_t)(l-1)*2*30,
                                            whh + (size_t)(l-1)*2*30*10,
                                            bhh + (size_t)(l-1)*2*30,
                                            dst);
        float* tmp = src; src = dst; dst = tmp;
    }
    head_kernel<<<96, 64, 0, stream>>>(src, lin_w, lin_b, out);
}

// Round 3
// 593.665 us; speedup vs baseline: 1.2823x; 1.0990x over previous
//
#include <hip/hip_runtime.h>
#include <math.h>

#define TT 84
#define BB 96
#define GB 6            // batches per group
#define NG 16           // groups (NG*GB == BB)
#define NTOK (TT*BB)

// Layouts:
//   xp0  (layer-0 gate inputs, global): [dir][t][b][30]
//   actG (even-layer activations + final, global): [t][b][20], c = dir*10 + j
//   actS (odd-layer activations, LDS per block):   [t][bl][20]
// mega kernel: 16 blocks x 128 threads. wave0 = fwd, wave1 = bwd, same 6 batches.
// Inter-layer sync = __syncthreads(); h exchange inside a wave = ds_bpermute.

__device__ __forceinline__ float sigm(float x)  { return 1.f/(1.f + __expf(-x)); }
__device__ __forceinline__ float ftanh(float x) { return 1.f - 2.f/(1.f + __expf(2.f*x)); }

// ---------------- layer-0 projection: emb gather + E=400 dot ----------------
__global__ __launch_bounds__(256) void proj0_kernel(
    const int* __restrict__ x, const float* __restrict__ emb,
    const float* __restrict__ wih0, const float* __restrict__ bih0,
    float* __restrict__ xp, unsigned int* __restrict__ bar)
{
    if (blockIdx.x == 0 && threadIdx.x == 0) bar[0] = 0u;  // re-zero barrier every call
    __shared__ float4 xrow[32][100];   // 32 tokens x 400 floats
    const int tok0 = blockIdx.x * 32;
    for (int u = threadIdx.x; u < 32*100; u += 256) {
        int tk = u / 100, i4 = u % 100;
        int row = x[tok0 + tk];
        xrow[tk][i4] = ((const float4*)emb)[row*100 + i4];
    }
    __syncthreads();
    const int g64 = threadIdx.x & 63;
    const int q   = threadIdx.x >> 6;          // 0..3, 8 tokens each
    if (g64 >= 60) return;
    const int dir = g64 / 30, gg = g64 % 30;
    const float bias = bih0[dir*30 + gg];
    float acc[8];
    #pragma unroll
    for (int c = 0; c < 8; ++c) acc[c] = bias;
    const float4* w4 = ((const float4*)wih0) + (dir*30 + gg)*100;
    for (int i4 = 0; i4 < 100; ++i4) {
        float4 w = w4[i4];
        #pragma unroll
        for (int c = 0; c < 8; ++c) {
            float4 xv = xrow[q*8 + c][i4];
            acc[c] += w.x*xv.x + w.y*xv.y + w.z*xv.z + w.w*xv.w;
        }
    }
    #pragma unroll
    for (int c = 0; c < 8; ++c) {
        int tok = tok0 + q*8 + c;
        int t = tok / BB, b = tok % BB;
        xp[((size_t)((dir*TT + t)*BB + b))*30 + gg] = acc[c];
    }
}

// ---------------- fused proj + scan for one layer (l >= 1) ----------------
// ODD layer: read LDS actS, write global actG. EVEN: read actG, write actS.
template<bool ODD>
__device__ __forceinline__ void run_layer(
    const float* __restrict__ wi, const float* __restrict__ bi,
    const float* __restrict__ wh, const float* __restrict__ bh,
    float* actS, float* __restrict__ actG,
    int bl, int j, bool act_ln, int b, int gbp, int dir, int dt, int t0)
{
    float wpr[20], wpz[20], wpn[20];
    {
        const float4* p0 = (const float4*)(wi + j*20);
        const float4* p1 = (const float4*)(wi + (10+j)*20);
        const float4* p2 = (const float4*)(wi + (20+j)*20);
        #pragma unroll
        for (int q = 0; q < 5; ++q) {
            float4 a = p0[q]; wpr[4*q]=a.x; wpr[4*q+1]=a.y; wpr[4*q+2]=a.z; wpr[4*q+3]=a.w;
            float4 c = p1[q]; wpz[4*q]=c.x; wpz[4*q+1]=c.y; wpz[4*q+2]=c.z; wpz[4*q+3]=c.w;
            float4 d = p2[q]; wpn[4*q]=d.x; wpn[4*q+1]=d.y; wpn[4*q+2]=d.z; wpn[4*q+3]=d.w;
        }
    }
    const float bir = bi[j], biz = bi[10+j], bin = bi[20+j];
    float wr[10], wz[10], wn[10];
    {
        const float2* p0 = (const float2*)(wh + j*10);
        const float2* p1 = (const float2*)(wh + (10+j)*10);
        const float2* p2 = (const float2*)(wh + (20+j)*10);
        #pragma unroll
        for (int q = 0; q < 5; ++q) {
            float2 a = p0[q]; wr[2*q]=a.x; wr[2*q+1]=a.y;
            float2 c = p1[q]; wz[2*q]=c.x; wz[2*q+1]=c.y;
            float2 d = p2[q]; wn[2*q]=d.x; wn[2*q+1]=d.y;
        }
    }
    const float bhr = bh[j], bhz = bh[10+j], bhn = bh[20+j];

    float h[10];
    #pragma unroll
    for (int k = 0; k < 10; ++k) h[k] = 0.f;
    float hown = 0.f;
    int t = t0;

    float4 A[5];
    {
        const float4* p = ODD ? (const float4*)&actS[(t*GB + bl)*20]
                              : (const float4*)&actG[(size_t)(t*BB + b)*20];
        #pragma unroll
        for (int q = 0; q < 5; ++q) A[q] = p[q];
    }

    for (int s = 0; s < TT; ++s) {
        // gate inputs for current t (A holds act[t]); independent of h
        float xr = bir, xz = biz, xn = bin;
        #pragma unroll
        for (int q = 0; q < 5; ++q) {
            float a0 = A[q].x, a1 = A[q].y, a2 = A[q].z, a3 = A[q].w;
            int c = q*4;
            xr = fmaf(wpr[c  ], a0, xr); xz = fmaf(wpz[c  ], a0, xz); xn = fmaf(wpn[c  ], a0, xn);
            xr = fmaf(wpr[c+1], a1, xr); xz = fmaf(wpz[c+1], a1, xz); xn = fmaf(wpn[c+1], a1, xn);
            xr = fmaf(wpr[c+2], a2, xr); xz = fmaf(wpz[c+2], a2, xz); xn = fmaf(wpn[c+2], a2, xn);
            xr = fmaf(wpr[c+3], a3, xr); xz = fmaf(wpz[c+3], a3, xz); xn = fmaf(wpn[c+3], a3, xn);
        }
        int tn = (s == TT-1) ? t : t + dt;
        {
            const float4* p = ODD ? (const float4*)&actS[(tn*GB + bl)*20]
                                  : (const float4*)&actG[(size_t)(tn*BB + b)*20];
            #pragma unroll
            for (int q = 0; q < 5; ++q) A[q] = p[q];
        }
        float hr0 = bhr, hz0 = bhz, hn0 = bhn, hr1 = 0.f, hz1 = 0.f, hn1 = 0.f;
        #pragma unroll
        for (int k = 0; k < 10; k += 2) {
            hr0 = fmaf(wr[k], h[k], hr0); hr1 = fmaf(wr[k+1], h[k+1], hr1);
            hz0 = fmaf(wz[k], h[k], hz0); hz1 = fmaf(wz[k+1], h[k+1], hz1);
            hn0 = fmaf(wn[k], h[k], hn0); hn1 = fmaf(wn[k+1], h[k+1], hn1);
        }
        float r = sigm(xr + hr0 + hr1);
        float z = sigm(xz + hz0 + hz1);
        float n = ftanh(xn + r*(hn0 + hn1));
        float hnew = n + z*(hown - n);
        if (act_ln) {
            if (ODD) actG[(size_t)(t*BB + b)*20 + dir*10 + j] = hnew;
            else     actS[(t*GB + bl)*20 + dir*10 + j] = hnew;
        }
        hown = hnew;
        int hv = __float_as_int(hnew);
        #pragma unroll
        for (int k = 0; k < 10; ++k)
            h[k] = __int_as_float(__builtin_amdgcn_ds_bpermute(gbp + k*4, hv));
        t = tn;
    }
}

// ---------------- mega: all 10 layers + head, 16 blocks x 128 ----------------
__global__ __launch_bounds__(128) void mega_kernel(
    const float* __restrict__ xp0,
    const float* __restrict__ whh0, const float* __restrict__ bhh0,
    const float* __restrict__ wih,  const float* __restrict__ bih,
    const float* __restrict__ whh,  const float* __restrict__ bhh,
    const float* __restrict__ lin_w, const float* __restrict__ lin_b,
    float* __restrict__ actG, unsigned int* __restrict__ bar,
    float* __restrict__ out)
{
    __shared__ float actS[TT*GB*20];     // 40320 B
    __shared__ float feat[GB*336];       //  8064 B

    const int tid  = threadIdx.x;
    const int dir  = tid >> 6;
    const int lane = tid & 63;
    int bl = lane / 10; if (bl > 5) bl = 5;
    int j  = lane - bl*10; if (j > 9) j = 9;
    const bool act_ln = (lane < 60);
    const int grp = blockIdx.x;
    const int b   = grp*GB + bl;
    const int gbp = bl*40;               // bpermute byte base (lane bl*10 + k)
    const int dt  = dir ? -1 : 1;
    const int t0  = dir ? TT-1 : 0;

    // ---- layer 0: read xp0 (global), write actS ----
    {
        float wr[10], wz[10], wn[10];
        const float* wh = whh0 + dir*300;
        {
            const float2* p0 = (const float2*)(wh + j*10);
            const float2* p1 = (const float2*)(wh + (10+j)*10);
            const float2* p2 = (const float2*)(wh + (20+j)*10);
            #pragma unroll
            for (int q = 0; q < 5; ++q) {
                float2 a = p0[q]; wr[2*q]=a.x; wr[2*q+1]=a.y;
                float2 c = p1[q]; wz[2*q]=c.x; wz[2*q+1]=c.y;
                float2 d = p2[q]; wn[2*q]=d.x; wn[2*q+1]=d.y;
            }
        }
        const float bhr = bhh0[dir*30 + j];
        const float bhz = bhh0[dir*30 + 10 + j];
        const float bhn = bhh0[dir*30 + 20 + j];

        float h[10];
        #pragma unroll
        for (int k = 0; k < 10; ++k) h[k] = 0.f;
        float hown = 0.f;
        int t = t0;
        const float* xb = xp0 + (size_t)dir*TT*BB*30;

        float xr = xb[(size_t)(t*BB + b)*30 + j];
        float xz = xb[(size_t)(t*BB + b)*30 + 10 + j];
        float xn = xb[(size_t)(t*BB + b)*30 + 20 + j];

        for (int s = 0; s < TT; ++s) {
            int tn = (s == TT-1) ? t : t + dt;
            float nxr = xb[(size_t)(tn*BB + b)*30 + j];
            float nxz = xb[(size_t)(tn*BB + b)*30 + 10 + j];
            float nxn = xb[(size_t)(tn*BB + b)*30 + 20 + j];

            float hr0 = bhr, hz0 = bhz, hn0 = bhn, hr1 = 0.f, hz1 = 0.f, hn1 = 0.f;
            #pragma unroll
            for (int k = 0; k < 10; k += 2) {
                hr0 = fmaf(wr[k], h[k], hr0); hr1 = fmaf(wr[k+1], h[k+1], hr1);
                hz0 = fmaf(wz[k], h[k], hz0); hz1 = fmaf(wz[k+1], h[k+1], hz1);
                hn0 = fmaf(wn[k], h[k], hn0); hn1 = fmaf(wn[k+1], h[k+1], hn1);
            }
            float r = sigm(xr + hr0 + hr1);
            float z = sigm(xz + hz0 + hz1);
            float n = ftanh(xn + r*(hn0 + hn1));
            float hnew = n + z*(hown - n);
            if (act_ln) actS[(t*GB + bl)*20 + dir*10 + j] = hnew;
            hown = hnew;
            int hv = __float_as_int(hnew);
            #pragma unroll
            for (int k = 0; k < 10; ++k)
                h[k] = __int_as_float(__builtin_amdgcn_ds_bpermute(gbp + k*4, hv));
            xr = nxr; xz = nxz; xn = nxn;
            t = tn;
        }
    }
    __syncthreads();

    // ---- layers 1..9 ----
    #pragma unroll 1
    for (int l = 1; l < 10; ++l) {
        const float* wi = wih + (size_t)((l-1)*2 + dir)*600;
        const float* bi = bih + (size_t)((l-1)*2 + dir)*30;
        const float* wh = whh + (size_t)((l-1)*2 + dir)*300;
        const float* bh = bhh + (size_t)((l-1)*2 + dir)*30;
        if (l & 1) run_layer<true >(wi, bi, wh, bh, actS, actG, bl, j, act_ln, b, gbp, dir, dt, t0);
        else       run_layer<false>(wi, bi, wh, bh, actS, actG, bl, j, act_ln, b, gbp, dir, dt, t0);
        __syncthreads();
    }

    // ---- grid barrier (16 blocks, all co-resident) ----
    __threadfence();
    __syncthreads();
    if (tid == 0) {
        __hip_atomic_fetch_add(bar, 1u, __ATOMIC_ACQ_REL, __HIP_MEMORY_SCOPE_AGENT);
        while (__hip_atomic_load(bar, __ATOMIC_ACQUIRE, __HIP_MEMORY_SCOPE_AGENT) < (unsigned)NG)
            __builtin_amdgcn_s_sleep(1);
    }
    __syncthreads();
    __threadfence();

    // ---- head: rows r = grp*6 .. grp*6+5 ----
    for (int u = tid; u < GB*336; u += 128) {
        int q = u / 336, v = u % 336;
        int r = grp*GB + q;
        int qq = v / 12, f = v % 12;
        int pair = r*28 + qq;           // t*32 + bb
        int t = pair / 32, bb = pair % 32;
        int jj = (f < 6) ? f : f - 6;
        float acc = (f < 6) ? 0.f : -1e30f;
        #pragma unroll
        for (int i = 0; i < 3; ++i) {
            #pragma unroll
            for (int kk = 0; kk < 3; ++kk) {
                float vv = actG[(size_t)(t*BB + bb*3 + i)*20 + jj*3 + kk];
                if (f < 6) acc += vv; else acc = fmaxf(acc, vv);
            }
        }
        feat[u] = (f < 6) ? acc*(1.f/9.f) : acc;
    }
    __syncthreads();
    if (tid < GB*19) {
        int q = tid / 19, o = tid % 19;
        int r = grp*GB + q;
        float acc = lin_b[o];
        const float* wrow = lin_w + o*336;
        const float* frow = feat + q*336;
        for (int v = 0; v < 336; ++v) acc = fmaf(frow[v], wrow[v], acc);
        out[r*19 + o] = sigm(acc);
    }
}

extern "C" void kernel_launch(void* const* d_in, const int* in_sizes, int n_in,
                              void* d_out, int out_size, void* d_ws, size_t ws_size,
                              hipStream_t stream)
{
    const int*   x     = (const int*)  d_in[0];
    const float* emb   = (const float*)d_in[1];
    const float* wih0  = (const float*)d_in[2];
    const float* whh0  = (const float*)d_in[3];
    const float* bih0  = (const float*)d_in[4];
    const float* bhh0  = (const float*)d_in[5];
    const float* wih   = (const float*)d_in[6];
    const float* whh   = (const float*)d_in[7];
    const float* bih   = (const float*)d_in[8];
    const float* bhh   = (const float*)d_in[9];
    const float* lin_w = (const float*)d_in[10];
    const float* lin_b = (const float*)d_in[11];
    float* out = (float*)d_out;

    float* xp0  = (float*)d_ws;                    // 2*84*96*30 = 483840 floats
    float* actG = xp0 + (size_t)2*NTOK*30;         // 84*96*20   = 161280 floats
    unsigned int* bar = (unsigned int*)(actG + (size_t)NTOK*20);

    proj0_kernel<<<252, 256, 0, stream>>>(x, emb, wih0, bih0, xp0, bar);
    mega_kernel<<<NG, 128, 0, stream>>>(xp0, whh0, bhh0, wih, bih, whh, bhh,
                                        lin_w, lin_b, actG, bar, out);
}

// Round 4
// 521.729 us; speedup vs baseline: 1.4591x; 1.1379x over previous
//
#include <hip/hip_runtime.h>
#include <math.h>

#define TT 84
#define BB 96
#define GB 6            // batches per group
#define NG 16           // groups (NG*GB == BB)
#define NTOK (TT*BB)

// Layouts:
//   xp0  (layer-0 gate inputs, global): [dir][t][b][30]
//   actA/actB (inter-layer activations, LDS): [t][bl][20], c = dir*10 + j
//   actG (final layer output, global): [t][b][20]
// mega kernel: 16 blocks x 128 threads (wave0=fwd, wave1=bwd, same 6 batches).
// launch_bounds(128,1): only 16 blocks exist -> trade occupancy for VGPRs so
// the per-layer weight set (60+30 floats) + pipeline buffers stay in registers.

__device__ __forceinline__ float frcp(float x)  { return __builtin_amdgcn_rcpf(x); }
__device__ __forceinline__ float sigm(float x)  { return frcp(1.f + __expf(-x)); }
__device__ __forceinline__ float ftanh(float x) { return 1.f - 2.f*frcp(1.f + __expf(2.f*x)); }

// ---------------- layer-0 projection: emb gather + E=400 dot ----------------
__global__ __launch_bounds__(256) void proj0_kernel(
    const int* __restrict__ x, const float* __restrict__ emb,
    const float* __restrict__ wih0, const float* __restrict__ bih0,
    float* __restrict__ xp, unsigned int* __restrict__ bar)
{
    if (blockIdx.x == 0 && threadIdx.x == 0) bar[0] = 0u;  // re-zero barrier every call
    __shared__ float4 xrow[32][100];   // 32 tokens x 400 floats
    const int tok0 = blockIdx.x * 32;
    for (int u = threadIdx.x; u < 32*100; u += 256) {
        int tk = u / 100, i4 = u % 100;
        int row = x[tok0 + tk];
        xrow[tk][i4] = ((const float4*)emb)[row*100 + i4];
    }
    __syncthreads();
    const int g64 = threadIdx.x & 63;
    const int q   = threadIdx.x >> 6;          // 0..3, 8 tokens each
    if (g64 >= 60) return;
    const int dir = g64 / 30, gg = g64 % 30;
    const float bias = bih0[dir*30 + gg];
    float acc[8];
    #pragma unroll
    for (int c = 0; c < 8; ++c) acc[c] = bias;
    const float4* w4 = ((const float4*)wih0) + (dir*30 + gg)*100;
    for (int i4 = 0; i4 < 100; ++i4) {
        float4 w = w4[i4];
        #pragma unroll
        for (int c = 0; c < 8; ++c) {
            float4 xv = xrow[q*8 + c][i4];
            acc[c] += w.x*xv.x + w.y*xv.y + w.z*xv.z + w.w*xv.w;
        }
    }
    #pragma unroll
    for (int c = 0; c < 8; ++c) {
        int tok = tok0 + q*8 + c;
        int t = tok / BB, b = tok % BB;
        xp[((size_t)((dir*TT + t)*BB + b))*30 + gg] = acc[c];
    }
}

// ---------------- helpers ----------------
__device__ __forceinline__ void proj20(
    const float4* A, const float* wpr, const float* wpz, const float* wpn,
    float bir, float biz, float bin, float& xr, float& xz, float& xn)
{
    xr = bir; xz = biz; xn = bin;
    #pragma unroll
    for (int q = 0; q < 5; ++q) {
        float a0 = A[q].x, a1 = A[q].y, a2 = A[q].z, a3 = A[q].w;
        int c = q*4;
        xr = fmaf(wpr[c  ], a0, xr); xz = fmaf(wpz[c  ], a0, xz); xn = fmaf(wpn[c  ], a0, xn);
        xr = fmaf(wpr[c+1], a1, xr); xz = fmaf(wpz[c+1], a1, xz); xn = fmaf(wpn[c+1], a1, xn);
        xr = fmaf(wpr[c+2], a2, xr); xz = fmaf(wpz[c+2], a2, xz); xn = fmaf(wpn[c+2], a2, xn);
        xr = fmaf(wpr[c+3], a3, xr); xz = fmaf(wpz[c+3], a3, xz); xn = fmaf(wpn[c+3], a3, xn);
    }
}

__device__ __forceinline__ float gru_step(
    float xr, float xz, float xn,
    const float* wr, const float* wz, const float* wn,
    float bhr, float bhz, float bhn, const float* h, float& hown)
{
    float hr0 = bhr, hz0 = bhz, hn0 = bhn, hr1 = 0.f, hz1 = 0.f, hn1 = 0.f;
    #pragma unroll
    for (int k = 0; k < 10; k += 2) {
        hr0 = fmaf(wr[k], h[k], hr0); hr1 = fmaf(wr[k+1], h[k+1], hr1);
        hz0 = fmaf(wz[k], h[k], hz0); hz1 = fmaf(wz[k+1], h[k+1], hz1);
        hn0 = fmaf(wn[k], h[k], hn0); hn1 = fmaf(wn[k+1], h[k+1], hn1);
    }
    float r = sigm(xr + hr0 + hr1);
    float z = sigm(xz + hz0 + hz1);
    float n = ftanh(xn + r*(hn0 + hn1));
    float hnew = n + z*(hown - n);
    hown = hnew;
    return hnew;
}

// fused proj + scan for layers 1..9; act in LDS, software-pipelined 2x.
template<bool LAST>
__device__ __forceinline__ void gru_mid(
    const float* __restrict__ wi, const float* __restrict__ bi,
    const float* __restrict__ wh, const float* __restrict__ bh,
    const float* act_in, float* act_out, float* __restrict__ actG,
    int bl, int j, bool act_ln, int b, int gbp, int dir, int dt, int t0)
{
    float wpr[20], wpz[20], wpn[20];
    {
        const float4* p0 = (const float4*)(wi + j*20);
        const float4* p1 = (const float4*)(wi + (10+j)*20);
        const float4* p2 = (const float4*)(wi + (20+j)*20);
        #pragma unroll
        for (int q = 0; q < 5; ++q) {
            float4 a = p0[q]; wpr[4*q]=a.x; wpr[4*q+1]=a.y; wpr[4*q+2]=a.z; wpr[4*q+3]=a.w;
            float4 c = p1[q]; wpz[4*q]=c.x; wpz[4*q+1]=c.y; wpz[4*q+2]=c.z; wpz[4*q+3]=c.w;
            float4 d = p2[q]; wpn[4*q]=d.x; wpn[4*q+1]=d.y; wpn[4*q+2]=d.z; wpn[4*q+3]=d.w;
        }
    }
    const float bir = bi[j], biz = bi[10+j], bin = bi[20+j];
    float wr[10], wz[10], wn[10];
    {
        const float2* p0 = (const float2*)(wh + j*10);
        const float2* p1 = (const float2*)(wh + (10+j)*10);
        const float2* p2 = (const float2*)(wh + (20+j)*10);
        #pragma unroll
        for (int q = 0; q < 5; ++q) {
            float2 a = p0[q]; wr[2*q]=a.x; wr[2*q+1]=a.y;
            float2 c = p1[q]; wz[2*q]=c.x; wz[2*q+1]=c.y;
            float2 d = p2[q]; wn[2*q]=d.x; wn[2*q+1]=d.y;
        }
    }
    const float bhr = bh[j], bhz = bh[10+j], bhn = bh[20+j];

    float h[10];
    #pragma unroll
    for (int k = 0; k < 10; ++k) h[k] = 0.f;
    float hown = 0.f;

    float4 Abuf[5], Bbuf[5];
    float xr_c, xz_c, xn_c, xr_n, xz_n, xn_n;

    // prologue: xp for step 0, then Abuf <- act[t(1)]
    {
        const float4* p = (const float4*)&act_in[(t0*GB + bl)*20];
        #pragma unroll
        for (int q = 0; q < 5; ++q) Abuf[q] = p[q];
        proj20(Abuf, wpr, wpz, wpn, bir, biz, bin, xr_c, xz_c, xn_c);
        const float4* p1 = (const float4*)&act_in[((t0 + dt)*GB + bl)*20];
        #pragma unroll
        for (int q = 0; q < 5; ++q) Abuf[q] = p1[q];
    }

    int t = t0;
    #pragma unroll 1
    for (int s = 0; s < TT; s += 2) {
        // ---- half 0: step s (time t). xp_c ready; Abuf = act[t+dt].
        {
            float hnew = gru_step(xr_c, xz_c, xn_c, wr, wz, wn, bhr, bhz, bhn, h, hown);
            if (act_ln) {
                if (LAST) actG[(size_t)(t*BB + b)*20 + dir*10 + j] = hnew;
                else      act_out[(t*GB + bl)*20 + dir*10 + j] = hnew;
            }
            int hv = __float_as_int(hnew);
            #pragma unroll
            for (int k = 0; k < 10; ++k)
                h[k] = __int_as_float(__builtin_amdgcn_ds_bpermute(gbp + k*4, hv));
            // fill the bpermute shadow: load act[t+2dt] and proj act[t+dt]
            int tl = t + 2*dt; tl = tl < 0 ? 0 : (tl > TT-1 ? TT-1 : tl);
            const float4* p = (const float4*)&act_in[(tl*GB + bl)*20];
            #pragma unroll
            for (int q = 0; q < 5; ++q) Bbuf[q] = p[q];
            proj20(Abuf, wpr, wpz, wpn, bir, biz, bin, xr_n, xz_n, xn_n);
            t += dt;
        }
        // ---- half 1: step s+1 (time t). xp_n ready; Bbuf = act[t+dt].
        {
            float hnew = gru_step(xr_n, xz_n, xn_n, wr, wz, wn, bhr, bhz, bhn, h, hown);
            if (act_ln) {
                if (LAST) actG[(size_t)(t*BB + b)*20 + dir*10 + j] = hnew;
                else      act_out[(t*GB + bl)*20 + dir*10 + j] = hnew;
            }
            int hv = __float_as_int(hnew);
            #pragma unroll
            for (int k = 0; k < 10; ++k)
                h[k] = __int_as_float(__builtin_amdgcn_ds_bpermute(gbp + k*4, hv));
            int tl = t + 2*dt; tl = tl < 0 ? 0 : (tl > TT-1 ? TT-1 : tl);
            const float4* p = (const float4*)&act_in[(tl*GB + bl)*20];
            #pragma unroll
            for (int q = 0; q < 5; ++q) Abuf[q] = p[q];
            proj20(Bbuf, wpr, wpz, wpn, bir, biz, bin, xr_c, xz_c, xn_c);
            t += dt;
        }
    }
}

// ---------------- mega: all 10 layers + head, 16 blocks x 128 ----------------
__global__ __launch_bounds__(128, 1) void mega_kernel(
    const float* __restrict__ xp0,
    const float* __restrict__ whh0, const float* __restrict__ bhh0,
    const float* __restrict__ wih,  const float* __restrict__ bih,
    const float* __restrict__ whh,  const float* __restrict__ bhh,
    const float* __restrict__ lin_w, const float* __restrict__ lin_b,
    float* __restrict__ actG, unsigned int* __restrict__ bar,
    float* __restrict__ out)
{
    __shared__ float actA[TT*GB*20];     // 40320 B
    __shared__ float actB[TT*GB*20];     // 40320 B
    __shared__ float feat[GB*336];       //  8064 B

    const int tid  = threadIdx.x;
    const int dir  = tid >> 6;
    const int lane = tid & 63;
    int bl = lane / 10; if (bl > 5) bl = 5;
    int j  = lane - bl*10; if (j > 9) j = 9;
    const bool act_ln = (lane < 60);
    const int grp = blockIdx.x;
    const int b   = grp*GB + bl;
    const int gbp = bl*40;               // bpermute byte base (lane bl*10 + k)
    const int dt  = dir ? -1 : 1;
    const int t0  = dir ? TT-1 : 0;

    // ---- layer 0: read xp0 (global, prefetched), write actA ----
    {
        float wr[10], wz[10], wn[10];
        const float* wh = whh0 + dir*300;
        {
            const float2* p0 = (const float2*)(wh + j*10);
            const float2* p1 = (const float2*)(wh + (10+j)*10);
            const float2* p2 = (const float2*)(wh + (20+j)*10);
            #pragma unroll
            for (int q = 0; q < 5; ++q) {
                float2 a = p0[q]; wr[2*q]=a.x; wr[2*q+1]=a.y;
                float2 c = p1[q]; wz[2*q]=c.x; wz[2*q+1]=c.y;
                float2 d = p2[q]; wn[2*q]=d.x; wn[2*q+1]=d.y;
            }
        }
        const float bhr = bhh0[dir*30 + j];
        const float bhz = bhh0[dir*30 + 10 + j];
        const float bhn = bhh0[dir*30 + 20 + j];

        float h[10];
        #pragma unroll
        for (int k = 0; k < 10; ++k) h[k] = 0.f;
        float hown = 0.f;
        int t = t0;
        const float* xb = xp0 + (size_t)dir*TT*BB*30;

        float xr = xb[(size_t)(t*BB + b)*30 + j];
        float xz = xb[(size_t)(t*BB + b)*30 + 10 + j];
        float xn = xb[(size_t)(t*BB + b)*30 + 20 + j];

        #pragma unroll 1
        for (int s = 0; s < TT; ++s) {
            int tn = (s == TT-1) ? t : t + dt;
            float nxr = xb[(size_t)(tn*BB + b)*30 + j];
            float nxz = xb[(size_t)(tn*BB + b)*30 + 10 + j];
            float nxn = xb[(size_t)(tn*BB + b)*30 + 20 + j];

            float hnew = gru_step(xr, xz, xn, wr, wz, wn, bhr, bhz, bhn, h, hown);
            if (act_ln) actA[(t*GB + bl)*20 + dir*10 + j] = hnew;
            int hv = __float_as_int(hnew);
            #pragma unroll
            for (int k = 0; k < 10; ++k)
                h[k] = __int_as_float(__builtin_amdgcn_ds_bpermute(gbp + k*4, hv));
            xr = nxr; xz = nxz; xn = nxn;
            t = tn;
        }
    }
    __syncthreads();

    // ---- layers 1..8 (LDS ping-pong), then layer 9 to global ----
    #pragma unroll 1
    for (int lp = 0; lp < 4; ++lp) {
        int l = 1 + lp*2;
        gru_mid<false>(wih + (size_t)((l-1)*2 + dir)*600, bih + (size_t)((l-1)*2 + dir)*30,
                       whh + (size_t)((l-1)*2 + dir)*300, bhh + (size_t)((l-1)*2 + dir)*30,
                       actA, actB, actG, bl, j, act_ln, b, gbp, dir, dt, t0);
        __syncthreads();
        l = 2 + lp*2;
        gru_mid<false>(wih + (size_t)((l-1)*2 + dir)*600, bih + (size_t)((l-1)*2 + dir)*30,
                       whh + (size_t)((l-1)*2 + dir)*300, bhh + (size_t)((l-1)*2 + dir)*30,
                       actB, actA, actG, bl, j, act_ln, b, gbp, dir, dt, t0);
        __syncthreads();
    }
    gru_mid<true>(wih + (size_t)(8*2 + dir)*600, bih + (size_t)(8*2 + dir)*30,
                  whh + (size_t)(8*2 + dir)*300, bhh + (size_t)(8*2 + dir)*30,
                  actA, actB, actG, bl, j, act_ln, b, gbp, dir, dt, t0);

    // ---- grid barrier (16 blocks, all co-resident) ----
    __threadfence();
    __syncthreads();
    if (tid == 0) {
        __hip_atomic_fetch_add(bar, 1u, __ATOMIC_ACQ_REL, __HIP_MEMORY_SCOPE_AGENT);
        while (__hip_atomic_load(bar, __ATOMIC_ACQUIRE, __HIP_MEMORY_SCOPE_AGENT) < (unsigned)NG)
            __builtin_amdgcn_s_sleep(1);
    }
    __syncthreads();
    __threadfence();

    // ---- head: rows r = grp*6 .. grp*6+5 ----
    for (int u = tid; u < GB*336; u += 128) {
        int q = u / 336, v = u % 336;
        int r = grp*GB + q;
        int qq = v / 12, f = v % 12;
        int pair = r*28 + qq;           // t*32 + bb
        int t = pair / 32, bb = pair % 32;
        int jj = (f < 6) ? f : f - 6;
        float acc = (f < 6) ? 0.f : -1e30f;
        #pragma unroll
        for (int i = 0; i < 3; ++i) {
            #pragma unroll
            for (int kk = 0; kk < 3; ++kk) {
                float vv = actG[(size_t)(t*BB + bb*3 + i)*20 + jj*3 + kk];
                if (f < 6) acc += vv; else acc = fmaxf(acc, vv);
            }
        }
        feat[u] = (f < 6) ? acc*(1.f/9.f) : acc;
    }
    __syncthreads();
    if (tid < GB*19) {
        int q = tid / 19, o = tid % 19;
        int r = grp*GB + q;
        float acc = lin_b[o];
        const float* wrow = lin_w + o*336;
        const float* frow = feat + q*336;
        for (int v = 0; v < 336; ++v) acc = fmaf(frow[v], wrow[v], acc);
        out[r*19 + o] = sigm(acc);
    }
}

extern "C" void kernel_launch(void* const* d_in, const int* in_sizes, int n_in,
                              void* d_out, int out_size, void* d_ws, size_t ws_size,
                              hipStream_t stream)
{
    const int*   x     = (const int*)  d_in[0];
    const float* emb   = (const float*)d_in[1];
    const float* wih0  = (const float*)d_in[2];
    const float* whh0  = (const float*)d_in[3];
    const float* bih0  = (const float*)d_in[4];
    const float* bhh0  = (const float*)d_in[5];
    const float* wih   = (const float*)d_in[6];
    const float* whh   = (const float*)d_in[7];
    const float* bih   = (const float*)d_in[8];
    const float* bhh   = (const float*)d_in[9];
    const float* lin_w = (const float*)d_in[10];
    const float* lin_b = (const float*)d_in[11];
    float* out = (float*)d_out;

    float* xp0  = (float*)d_ws;                    // 2*84*96*30 = 483840 floats
    float* actG = xp0 + (size_t)2*NTOK*30;         // 84*96*20   = 161280 floats
    unsigned int* bar = (unsigned int*)(actG + (size_t)NTOK*20);

    proj0_kernel<<<252, 256, 0, stream>>>(x, emb, wih0, bih0, xp0, bar);
    mega_kernel<<<NG, 128, 0, stream>>>(xp0, whh0, bhh0, wih, bih, whh, bhh,
                                        lin_w, lin_b, actG, bar, out);
}

// Round 5
// 485.873 us; speedup vs baseline: 1.5668x; 1.0738x over previous
//
#include <hip/hip_runtime.h>
#include <math.h>

#define TT 84
#define BB 96
#define GB 6            // batches per group
#define NG 16           // groups (NG*GB == BB)
#define NTOK (TT*BB)
#define RW4 6           // float4s per act row: 24 floats = [fwd 10 | pad 2 | bwd 10 | pad 2]

// Gate-argument pre-scaling folded into weights/biases:
//  r,z rows scaled by -log2(e)   -> sigm(a) = rcp(1 + exp2(arg))
//  n rows scaled by -2*log2(e)   -> tanh(x) = 2*rcp(1 + exp2(arg)) - 1
#define S_RZ (-1.4426950408889634f)
#define S_N  (-2.8853900817779268f)

__device__ __forceinline__ float frcp(float x)  { return __builtin_amdgcn_rcpf(x); }
__device__ __forceinline__ float fexp2(float x) { return __builtin_amdgcn_exp2f(x); }

// ---------------- layer-0 projection: emb gather + E=400 dot (pre-scaled) ----
__global__ __launch_bounds__(256) void proj0_kernel(
    const int* __restrict__ x, const float* __restrict__ emb,
    const float* __restrict__ wih0, const float* __restrict__ bih0,
    float* __restrict__ xp, unsigned int* __restrict__ bar)
{
    if (blockIdx.x == 0 && threadIdx.x == 0) bar[0] = 0u;  // re-zero grid barrier
    __shared__ float4 xrow[32][100];   // 32 tokens x 400 floats
    const int tok0 = blockIdx.x * 32;
    for (int u = threadIdx.x; u < 32*100; u += 256) {
        int tk = u / 100, i4 = u % 100;
        int row = x[tok0 + tk];
        xrow[tk][i4] = ((const float4*)emb)[row*100 + i4];
    }
    __syncthreads();
    const int g64 = threadIdx.x & 63;
    const int q   = threadIdx.x >> 6;          // 0..3, 8 tokens each
    if (g64 >= 60) return;
    const int dir = g64 / 30, gg = g64 % 30;
    const float sc = (gg < 20) ? S_RZ : S_N;
    const float bias = bih0[dir*30 + gg];
    float acc[8];
    #pragma unroll
    for (int c = 0; c < 8; ++c) acc[c] = bias;
    const float4* w4 = ((const float4*)wih0) + (dir*30 + gg)*100;
    for (int i4 = 0; i4 < 100; ++i4) {
        float4 w = w4[i4];
        #pragma unroll
        for (int c = 0; c < 8; ++c) {
            float4 xv = xrow[q*8 + c][i4];
            acc[c] += w.x*xv.x + w.y*xv.y + w.z*xv.z + w.w*xv.w;
        }
    }
    #pragma unroll
    for (int c = 0; c < 8; ++c) {
        int tok = tok0 + q*8 + c;
        int t = tok / BB, b = tok % BB;
        xp[((size_t)((dir*TT + t)*BB + b))*30 + gg] = acc[c]*sc;
    }
}

// ---------------- GRU cell: pre-scaled args, h from exchange float4s ---------
__device__ __forceinline__ float gru_cell(
    float xr, float xz, float xn,
    float4 ha, float4 hb, float4 hc,
    const float* wr, const float* wz, const float* wn,
    float bhr, float bhz, float bhn, float& hown)
{
    float hr0 = fmaf(wr[0], ha.x, bhr), hr1 = wr[1]*ha.y;
    float hz0 = fmaf(wz[0], ha.x, bhz), hz1 = wz[1]*ha.y;
    float hn0 = fmaf(wn[0], ha.x, bhn), hn1 = wn[1]*ha.y;
    hr0 = fmaf(wr[2], ha.z, hr0); hr1 = fmaf(wr[3], ha.w, hr1);
    hz0 = fmaf(wz[2], ha.z, hz0); hz1 = fmaf(wz[3], ha.w, hz1);
    hn0 = fmaf(wn[2], ha.z, hn0); hn1 = fmaf(wn[3], ha.w, hn1);
    hr0 = fmaf(wr[4], hb.x, hr0); hr1 = fmaf(wr[5], hb.y, hr1);
    hz0 = fmaf(wz[4], hb.x, hz0); hz1 = fmaf(wz[5], hb.y, hz1);
    hn0 = fmaf(wn[4], hb.x, hn0); hn1 = fmaf(wn[5], hb.y, hn1);
    hr0 = fmaf(wr[6], hb.z, hr0); hr1 = fmaf(wr[7], hb.w, hr1);
    hz0 = fmaf(wz[6], hb.z, hz0); hz1 = fmaf(wz[7], hb.w, hz1);
    hn0 = fmaf(wn[6], hb.z, hn0); hn1 = fmaf(wn[7], hb.w, hn1);
    hr0 = fmaf(wr[8], hc.x, hr0); hr1 = fmaf(wr[9], hc.y, hr1);
    hz0 = fmaf(wz[8], hc.x, hz0); hz1 = fmaf(wz[9], hc.y, hz1);
    hn0 = fmaf(wn[8], hc.x, hn0); hn1 = fmaf(wn[9], hc.y, hn1);
    float r = frcp(1.f + fexp2(xr + hr0 + hr1));
    float z = frcp(1.f + fexp2(xz + hz0 + hz1));
    float an = fmaf(r, hn0 + hn1, xn);
    float n  = fmaf(2.f, frcp(1.f + fexp2(an)), -1.f);
    float hnew = n + z*(hown - n);
    hown = hnew;
    return hnew;
}

// proj over 20 channels from a padded 24-float act row
__device__ __forceinline__ void proj20(
    const float4* A, const float* wpr, const float* wpz, const float* wpn,
    float bir, float biz, float bin, float& xr, float& xz, float& xn)
{
    float a[24];
    #pragma unroll
    for (int q = 0; q < 6; ++q) {
        a[4*q]=A[q].x; a[4*q+1]=A[q].y; a[4*q+2]=A[q].z; a[4*q+3]=A[q].w;
    }
    xr = bir; xz = biz; xn = bin;
    #pragma unroll
    for (int c = 0; c < 20; ++c) {
        float av = a[c + (c >= 10 ? 2 : 0)];
        xr = fmaf(wpr[c], av, xr); xz = fmaf(wpz[c], av, xz); xn = fmaf(wpn[c], av, xn);
    }
}

// ---------------- fused proj + scan for layers 1..9 --------------------------
template<bool LAST>
__device__ __forceinline__ void gru_mid(
    const float* __restrict__ wi, const float* __restrict__ bi,
    const float* __restrict__ wh, const float* __restrict__ bh,
    const float4* in4, float4* out4, float* __restrict__ actG,
    int bl, int j, bool act_ln, int b, int dir, int dt, int t0)
{
    float wpr[20], wpz[20], wpn[20];
    {
        const float4* p0 = (const float4*)(wi + j*20);
        const float4* p1 = (const float4*)(wi + (10+j)*20);
        const float4* p2 = (const float4*)(wi + (20+j)*20);
        #pragma unroll
        for (int q = 0; q < 5; ++q) {
            float4 a = p0[q]; wpr[4*q]=a.x*S_RZ; wpr[4*q+1]=a.y*S_RZ; wpr[4*q+2]=a.z*S_RZ; wpr[4*q+3]=a.w*S_RZ;
            float4 c = p1[q]; wpz[4*q]=c.x*S_RZ; wpz[4*q+1]=c.y*S_RZ; wpz[4*q+2]=c.z*S_RZ; wpz[4*q+3]=c.w*S_RZ;
            float4 d = p2[q]; wpn[4*q]=d.x*S_N;  wpn[4*q+1]=d.y*S_N;  wpn[4*q+2]=d.z*S_N;  wpn[4*q+3]=d.w*S_N;
        }
    }
    const float bir = bi[j]*S_RZ, biz = bi[10+j]*S_RZ, bin = bi[20+j]*S_N;
    float wr[10], wz[10], wn[10];
    {
        const float2* p0 = (const float2*)(wh + j*10);
        const float2* p1 = (const float2*)(wh + (10+j)*10);
        const float2* p2 = (const float2*)(wh + (20+j)*10);
        #pragma unroll
        for (int q = 0; q < 5; ++q) {
            float2 a = p0[q]; wr[2*q]=a.x*S_RZ; wr[2*q+1]=a.y*S_RZ;
            float2 c = p1[q]; wz[2*q]=c.x*S_RZ; wz[2*q+1]=c.y*S_RZ;
            float2 d = p2[q]; wn[2*q]=d.x*S_N;  wn[2*q+1]=d.y*S_N;
        }
    }
    const float bhr = bh[j]*S_RZ, bhz = bh[10+j]*S_RZ, bhn = bh[20+j]*S_N;

    float4 ha = {0,0,0,0}, hb = {0,0,0,0}, hc = {0,0,0,0};
    float hown = 0.f;
    float4 A[6], B[6];
    float xr_c, xz_c, xn_c, xr_n, xz_n, xn_n;
    int t = t0;
    {
        const float4* p0 = &in4[(t0*GB + bl)*RW4];
        #pragma unroll
        for (int q = 0; q < 6; ++q) B[q] = p0[q];
        const float4* p1 = &in4[((t0 + dt)*GB + bl)*RW4];
        #pragma unroll
        for (int q = 0; q < 6; ++q) A[q] = p1[q];
        proj20(B, wpr, wpz, wpn, bir, biz, bin, xr_c, xz_c, xn_c);
    }

    #pragma unroll 1
    for (int s = 0; s < TT; s += 2) {
        // ---- half 0: time t, gate inputs xr_c; prefetch into B, proj A.
        {
            float hnew = gru_cell(xr_c, xz_c, xn_c, ha, hb, hc, wr, wz, wn, bhr, bhz, bhn, hown);
            ((float*)&out4[(t*GB + bl)*RW4])[dir*12 + j] = hnew;   // ds_write (exchange + act)
            const float4* hr = &out4[(t*GB + bl)*RW4 + dir*3];
            ha = hr[0]; hb = hr[1]; hc = hr[2];                    // 3x ds_read_b128
            __builtin_amdgcn_sched_barrier(0);                     // keep h-reads oldest in lgkm queue
            if (LAST && act_ln) actG[(size_t)(t*BB + b)*20 + dir*10 + j] = hnew;
            int tl = t + 2*dt; tl = tl < 0 ? 0 : (tl > TT-1 ? TT-1 : tl);
            const float4* pl = &in4[(tl*GB + bl)*RW4];
            #pragma unroll
            for (int q = 0; q < 6; ++q) B[q] = pl[q];
            proj20(A, wpr, wpz, wpn, bir, biz, bin, xr_n, xz_n, xn_n);
            t += dt;
        }
        // ---- half 1: time t, gate inputs xr_n; prefetch into A, proj B.
        {
            float hnew = gru_cell(xr_n, xz_n, xn_n, ha, hb, hc, wr, wz, wn, bhr, bhz, bhn, hown);
            ((float*)&out4[(t*GB + bl)*RW4])[dir*12 + j] = hnew;
            const float4* hr = &out4[(t*GB + bl)*RW4 + dir*3];
            ha = hr[0]; hb = hr[1]; hc = hr[2];
            __builtin_amdgcn_sched_barrier(0);
            if (LAST && act_ln) actG[(size_t)(t*BB + b)*20 + dir*10 + j] = hnew;
            int tl = t + 2*dt; tl = tl < 0 ? 0 : (tl > TT-1 ? TT-1 : tl);
            const float4* pl = &in4[(tl*GB + bl)*RW4];
            #pragma unroll
            for (int q = 0; q < 6; ++q) A[q] = pl[q];
            proj20(B, wpr, wpz, wpn, bir, biz, bin, xr_c, xz_c, xn_c);
            t += dt;
        }
    }
}

// ---------------- mega: all 10 layers + head, 16 blocks x 128 ----------------
__global__ __launch_bounds__(128, 1) void mega_kernel(
    const float* __restrict__ xp0,
    const float* __restrict__ whh0, const float* __restrict__ bhh0,
    const float* __restrict__ wih,  const float* __restrict__ bih,
    const float* __restrict__ whh,  const float* __restrict__ bhh,
    const float* __restrict__ lin_w, const float* __restrict__ lin_b,
    float* __restrict__ actG, unsigned int* __restrict__ bar,
    float* __restrict__ out)
{
    __shared__ float4 actA4[TT*GB*RW4];    // 48384 B
    __shared__ float4 actB4[TT*GB*RW4];    // 48384 B  (feat aliases actA4 after layers)

    const int tid  = threadIdx.x;
    const int dir  = tid >> 6;
    const int lane = tid & 63;
    int bl = lane / 10; if (bl > 5) bl = 5;
    int j  = lane - bl*10; if (j > 9) j = 9;
    const bool act_ln = (lane < 60);
    const int grp = blockIdx.x;
    const int b   = grp*GB + bl;
    const int dt  = dir ? -1 : 1;
    const int t0  = dir ? TT-1 : 0;

    // ---- layer 0: read xp0 (global, prefetched), write actA ----
    {
        float wr[10], wz[10], wn[10];
        const float* wh = whh0 + dir*300;
        {
            const float2* p0 = (const float2*)(wh + j*10);
            const float2* p1 = (const float2*)(wh + (10+j)*10);
            const float2* p2 = (const float2*)(wh + (20+j)*10);
            #pragma unroll
            for (int q = 0; q < 5; ++q) {
                float2 a = p0[q]; wr[2*q]=a.x*S_RZ; wr[2*q+1]=a.y*S_RZ;
                float2 c = p1[q]; wz[2*q]=c.x*S_RZ; wz[2*q+1]=c.y*S_RZ;
                float2 d = p2[q]; wn[2*q]=d.x*S_N;  wn[2*q+1]=d.y*S_N;
            }
        }
        const float bhr = bhh0[dir*30 + j]*S_RZ;
        const float bhz = bhh0[dir*30 + 10 + j]*S_RZ;
        const float bhn = bhh0[dir*30 + 20 + j]*S_N;

        float4 ha = {0,0,0,0}, hb = {0,0,0,0}, hc = {0,0,0,0};
        float hown = 0.f;
        int t = t0;
        const float* xb = xp0 + (size_t)dir*TT*BB*30;

        float xr_c = xb[(size_t)(t*BB + b)*30 + j];
        float xz_c = xb[(size_t)(t*BB + b)*30 + 10 + j];
        float xn_c = xb[(size_t)(t*BB + b)*30 + 20 + j];

        #pragma unroll 1
        for (int s = 0; s < TT; ++s) {
            float hnew = gru_cell(xr_c, xz_c, xn_c, ha, hb, hc, wr, wz, wn, bhr, bhz, bhn, hown);
            ((float*)&actA4[(t*GB + bl)*RW4])[dir*12 + j] = hnew;
            const float4* hr = &actA4[(t*GB + bl)*RW4 + dir*3];
            ha = hr[0]; hb = hr[1]; hc = hr[2];
            __builtin_amdgcn_sched_barrier(0);
            int tn = (s == TT-1) ? t : t + dt;
            xr_c = xb[(size_t)(tn*BB + b)*30 + j];
            xz_c = xb[(size_t)(tn*BB + b)*30 + 10 + j];
            xn_c = xb[(size_t)(tn*BB + b)*30 + 20 + j];
            t = tn;
        }
    }
    __syncthreads();

    // ---- layers 1..8 (LDS ping-pong), then layer 9 to global ----
    #pragma unroll 1
    for (int lp = 0; lp < 4; ++lp) {
        int l = 1 + lp*2;
        gru_mid<false>(wih + (size_t)((l-1)*2 + dir)*600, bih + (size_t)((l-1)*2 + dir)*30,
                       whh + (size_t)((l-1)*2 + dir)*300, bhh + (size_t)((l-1)*2 + dir)*30,
                       actA4, actB4, actG, bl, j, act_ln, b, dir, dt, t0);
        __syncthreads();
        l = 2 + lp*2;
        gru_mid<false>(wih + (size_t)((l-1)*2 + dir)*600, bih + (size_t)((l-1)*2 + dir)*30,
                       whh + (size_t)((l-1)*2 + dir)*300, bhh + (size_t)((l-1)*2 + dir)*30,
                       actB4, actA4, actG, bl, j, act_ln, b, dir, dt, t0);
        __syncthreads();
    }
    gru_mid<true>(wih + (size_t)(8*2 + dir)*600, bih + (size_t)(8*2 + dir)*30,
                  whh + (size_t)(8*2 + dir)*300, bhh + (size_t)(8*2 + dir)*30,
                  actA4, actB4, actG, bl, j, act_ln, b, dir, dt, t0);

    // ---- grid barrier (16 blocks, all co-resident) ----
    __threadfence();
    __syncthreads();
    if (tid == 0) {
        __hip_atomic_fetch_add(bar, 1u, __ATOMIC_ACQ_REL, __HIP_MEMORY_SCOPE_AGENT);
        while (__hip_atomic_load(bar, __ATOMIC_ACQUIRE, __HIP_MEMORY_SCOPE_AGENT) < (unsigned)NG)
            __builtin_amdgcn_s_sleep(1);
    }
    __syncthreads();
    __threadfence();

    // ---- head: rows r = grp*6 .. grp*6+5 (feat aliases actA4) ----
    float* feat = (float*)actA4;
    for (int u = tid; u < GB*336; u += 128) {
        int q = u / 336, v = u % 336;
        int r = grp*GB + q;
        int qq = v / 12, f = v % 12;
        int pair = r*28 + qq;           // t*32 + bb
        int t = pair / 32, bb = pair % 32;
        int jj = (f < 6) ? f : f - 6;
        float acc = (f < 6) ? 0.f : -1e30f;
        #pragma unroll
        for (int i = 0; i < 3; ++i) {
            #pragma unroll
            for (int kk = 0; kk < 3; ++kk) {
                float vv = actG[(size_t)(t*BB + bb*3 + i)*20 + jj*3 + kk];
                if (f < 6) acc += vv; else acc = fmaxf(acc, vv);
            }
        }
        feat[u] = (f < 6) ? acc*(1.f/9.f) : acc;
    }
    __syncthreads();
    if (tid < GB*19) {
        int q = tid / 19, o = tid % 19;
        int r = grp*GB + q;
        float acc = lin_b[o];
        const float* wrow = lin_w + o*336;
        const float* frow = feat + q*336;
        for (int v = 0; v < 336; ++v) acc = fmaf(frow[v], wrow[v], acc);
        out[r*19 + o] = frcp(1.f + __expf(-acc));
    }
}

extern "C" void kernel_launch(void* const* d_in, const int* in_sizes, int n_in,
                              void* d_out, int out_size, void* d_ws, size_t ws_size,
                              hipStream_t stream)
{
    const int*   x     = (const int*)  d_in[0];
    const float* emb   = (const float*)d_in[1];
    const float* wih0  = (const float*)d_in[2];
    const float* whh0  = (const float*)d_in[3];
    const float* bih0  = (const float*)d_in[4];
    const float* bhh0  = (const float*)d_in[5];
    const float* wih   = (const float*)d_in[6];
    const float* whh   = (const float*)d_in[7];
    const float* bih   = (const float*)d_in[8];
    const float* bhh   = (const float*)d_in[9];
    const float* lin_w = (const float*)d_in[10];
    const float* lin_b = (const float*)d_in[11];
    float* out = (float*)d_out;

    float* xp0  = (float*)d_ws;                    // 2*84*96*30 = 483840 floats
    float* actG = xp0 + (size_t)2*NTOK*30;         // 84*96*20   = 161280 floats
    unsigned int* bar = (unsigned int*)(actG + (size_t)NTOK*20);

    proj0_kernel<<<252, 256, 0, stream>>>(x, emb, wih0, bih0, xp0, bar);
    mega_kernel<<<NG, 128, 0, stream>>>(xp0, whh0, bhh0, wih, bih, whh, bhh,
                                        lin_w, lin_b, actG, bar, out);
}